// Round 6
// baseline (102.292 us; speedup 1.0000x reference)
//
#include <hip/hip_runtime.h>
#include <math.h>
#include <stdint.h>

#define NR    2048   // rows (n)
#define NB    2048   // batch (b)
#define DIMD  64
#define KC    576    // 512 cross + 64 gram
#define BK    64
#define KSTEP 9      // 576 / 64

typedef __bf16 bf16x8 __attribute__((ext_vector_type(8)));
typedef float  f32x4  __attribute__((ext_vector_type(4)));

typedef const __attribute__((address_space(1))) void* gas_p;
typedef __attribute__((address_space(3))) void*       las_p;

__device__ __forceinline__ unsigned short f2bf(float f) {
    unsigned int u = __float_as_uint(f);
    unsigned int r = u + 0x7FFFu + ((u >> 16) & 1u);
    return (unsigned short)(r >> 16);
}

// ---- fused prep: blocks [0,512) build A'/cc/gcg, [512,1024) build B' -------
// block 0 also zeroes d_out (stream order guarantees this precedes the GEMM).
__global__ __launch_bounds__(256) void prep_all(
    const int*   __restrict__ col_indices,
    const float* __restrict__ col_times,
    const float* __restrict__ z_cols,
    const float* __restrict__ gamma_cols,
    const float* __restrict__ z_rows,
    unsigned short* __restrict__ Abuf,
    unsigned short* __restrict__ Bbuf,
    float* __restrict__ cc, float* __restrict__ gcg,
    float* __restrict__ out)
{
    const int tid = threadIdx.x, w = tid >> 6, lane = tid & 63;
    if (blockIdx.x == 0 && tid == 0) *out = 0.f;
    if (blockIdx.x < 512) {
        __shared__ float Tl[4][8];
        const int b  = blockIdx.x * 4 + w;
        const float t  = col_times[b];
        const int   ci = col_indices[b];
        if (lane < 8) {                       // T[o] = t^o / o!
            float v = 1.f;
            for (int i = 1; i <= lane; ++i) v = v * t / (float)i;
            Tl[w][lane] = v;
        }
        __syncthreads();
        const float cd = z_cols[ci * DIMD + lane];
        unsigned short* arow = Abuf + (size_t)b * KC;
#pragma unroll
        for (int o = 0; o < 8; ++o)
            arow[o * 64 + lane] = f2bf(-2.f * Tl[w][o] * cd);
        arow[512 + lane] = f2bf(Tl[w][lane >> 3] * Tl[w][lane & 7]);
        float s = cd * cd;
#pragma unroll
        for (int m = 1; m < 64; m <<= 1) s += __shfl_xor(s, m, 64);
        if (lane == 0) { cc[b] = s; gcg[b] = gamma_cols[ci]; }
    } else {
        const int n = (blockIdx.x - 512) * 4 + w;
        float z8[8];
#pragma unroll
        for (int o = 0; o < 8; ++o)
            z8[o] = z_rows[o * (NR * DIMD) + n * DIMD + lane];
        unsigned short* brow = Bbuf + (size_t)n * KC;
#pragma unroll
        for (int o = 0; o < 8; ++o)
            brow[o * 64 + lane] = f2bf(z8[o]);
        float myG = 0.f;
#pragma unroll
        for (int o1 = 0; o1 < 8; ++o1)
#pragma unroll
            for (int o2 = o1; o2 < 8; ++o2) {
                float p = z8[o1] * z8[o2];
#pragma unroll
                for (int m = 1; m < 64; m <<= 1) p += __shfl_xor(p, m, 64);
                if (lane == o1 * 8 + o2) myG = p;
                if (o1 != o2 && lane == o2 * 8 + o1) myG = p;
            }
        brow[512 + lane] = f2bf(myG);
    }
}

// ---- main: S = A' * B'^T via MFMA, dbuf 2-phase, fused loss ----------------
// tile 64(b) x 64(n), BK=64, 4 waves (2x2), wave tile 32x32, 4 blocks/CU.
// LDS rows 128B: XOR swizzle (pre-swizzled global source + swizzled read,
// linear gload_lds dest). STAGE(next) issued before compute(cur), one
// __syncthreads per K-step.
__global__ __launch_bounds__(256, 4) void p2v_gemm(
    const unsigned short* __restrict__ Abuf,
    const unsigned short* __restrict__ Bbuf,
    const float* __restrict__ cc,
    const float* __restrict__ gcg,
    const float* __restrict__ gamma_rows,
    const int*   __restrict__ events,
    float*       __restrict__ out)
{
    __shared__ unsigned short As[2][64 * BK] __attribute__((aligned(16))); // 16KB
    __shared__ unsigned short Bs[2][64 * BK] __attribute__((aligned(16))); // 16KB
    __shared__ float warr[4];

    const int tid = threadIdx.x, w = tid >> 6, lane = tid & 63;
    const int wm = w >> 1, wn = w & 1;
    const int n0 = blockIdx.x * 64, b0 = blockIdx.y * 64;

    // staging: each gload_lds moves 8 rows x 128B (1KB); per wave 2x A + 2x B.
    // lane -> row-in-group = lane>>3, source 16B chunk = (lane&7) ^ (row&7)
    const int lr8 = lane >> 3;
    const int cx  = (lane & 7) ^ lr8;
    const size_t gA = (size_t)(b0 + w * 16 + lr8) * KC + cx * 8;
    const size_t gB = (size_t)(n0 + w * 16 + lr8) * KC + cx * 8;
    const int dAo = (w * 16) * BK;   // element offset within a buffer
    const int dBo = (w * 16) * BK;

    f32x4 acc[2][2];
#pragma unroll
    for (int mi = 0; mi < 2; ++mi)
#pragma unroll
        for (int ni = 0; ni < 2; ++ni) acc[mi][ni] = (f32x4)(0.f);

#define STAGE(buf, ks)                                                         \
    {                                                                          \
        const int ko_ = (ks) * BK;                                             \
        _Pragma("unroll")                                                      \
        for (int i = 0; i < 2; ++i)                                            \
            __builtin_amdgcn_global_load_lds(                                  \
                (gas_p)(Abuf + gA + (size_t)(i * 8) * KC + ko_),               \
                (las_p)&As[buf][dAo + i * 512], 16, 0, 0);                     \
        _Pragma("unroll")                                                      \
        for (int i = 0; i < 2; ++i)                                            \
            __builtin_amdgcn_global_load_lds(                                  \
                (gas_p)(Bbuf + gB + (size_t)(i * 8) * KC + ko_),               \
                (las_p)&Bs[buf][dBo + i * 512], 16, 0, 0);                     \
    }

    STAGE(0, 0);
    __syncthreads();

#pragma unroll
    for (int ks = 0; ks < KSTEP; ++ks) {
        const int cur = ks & 1;
        if (ks + 1 < KSTEP) STAGE(cur ^ 1, ks + 1);
#pragma unroll
        for (int kk = 0; kk < 2; ++kk) {
            const int slot = (kk * 4 + (lane >> 4)) ^ (lane & 7);  // ^ (row&7)
            bf16x8 af[2], bfr[2];
#pragma unroll
            for (int mi = 0; mi < 2; ++mi)
                af[mi] = *reinterpret_cast<const bf16x8*>(
                    &As[cur][(wm * 32 + mi * 16 + (lane & 15)) * BK + slot * 8]);
#pragma unroll
            for (int ni = 0; ni < 2; ++ni)
                bfr[ni] = *reinterpret_cast<const bf16x8*>(
                    &Bs[cur][(wn * 32 + ni * 16 + (lane & 15)) * BK + slot * 8]);
#pragma unroll
            for (int mi = 0; mi < 2; ++mi)
#pragma unroll
                for (int ni = 0; ni < 2; ++ni)
                    acc[mi][ni] = __builtin_amdgcn_mfma_f32_16x16x32_bf16(
                        af[mi], bfr[ni], acc[mi][ni], 0, 0, 0);
        }
        __syncthreads();
    }
#undef STAGE

    // epilogue: dist^2 = S + cc[b]; loss = softplus(+/-logit); reduce
    float ls = 0.f;
#pragma unroll
    for (int ni = 0; ni < 2; ++ni) {
        const int n = n0 + wn * 32 + ni * 16 + (lane & 15);
        const float grn = gamma_rows[n];
        const size_t erow = (size_t)n * NB;
#pragma unroll
        for (int mi = 0; mi < 2; ++mi) {
            const int bb = b0 + wm * 32 + mi * 16 + (lane >> 4) * 4;
            const int4   ev  = *reinterpret_cast<const int4*>(&events[erow + bb]);
            const float4 ccv = *reinterpret_cast<const float4*>(&cc[bb]);
            const float4 gcv = *reinterpret_cast<const float4*>(&gcg[bb]);
#define EPJ(cmp, evv)                                                      \
            {                                                              \
                const float d2   = acc[mi][ni].cmp + ccv.cmp;              \
                const float dist = sqrtf(fmaxf(d2, 0.f));                  \
                const float L    = grn + gcv.cmp - dist;                   \
                const float x    = (evv != 0) ? -L : L;                    \
                ls += fmaxf(x, 0.f) + __logf(1.f + __expf(-fabsf(x)));     \
            }
            EPJ(x, ev.x) EPJ(y, ev.y) EPJ(z, ev.z) EPJ(w, ev.w)
#undef EPJ
        }
    }
#pragma unroll
    for (int m = 1; m < 64; m <<= 1) ls += __shfl_xor(ls, m, 64);
    if (lane == 0) warr[w] = ls;
    __syncthreads();
    if (tid == 0) atomicAdd(out, warr[0] + warr[1] + warr[2] + warr[3]);
}

extern "C" void kernel_launch(void* const* d_in, const int* in_sizes, int n_in,
                              void* d_out, int out_size, void* d_ws, size_t ws_size,
                              hipStream_t stream) {
    const int*   events      = (const int*)  d_in[0];
    const int*   col_indices = (const int*)  d_in[1];
    const float* col_times   = (const float*)d_in[2];
    const float* z_rows      = (const float*)d_in[3];
    const float* z_cols      = (const float*)d_in[4];
    const float* gamma_rows  = (const float*)d_in[5];
    const float* gamma_cols  = (const float*)d_in[6];
    float*       out         = (float*)d_out;

    unsigned short* Abuf = (unsigned short*)d_ws;                // 2048*576 bf16
    unsigned short* Bbuf = Abuf + (size_t)NB * KC;               // 2048*576 bf16
    float*          cc   = (float*)(Bbuf + (size_t)NR * KC);     // 2048 f32
    float*          gcg  = cc + NB;                              // 2048 f32

    prep_all<<<1024, 256, 0, stream>>>(col_indices, col_times, z_cols, gamma_cols,
                                       z_rows, Abuf, Bbuf, cc, gcg, out);
    dim3 grid(NR / 64, NB / 64);
    p2v_gemm<<<grid, 256, 0, stream>>>(Abuf, Bbuf, cc, gcg, gamma_rows, events, out);
}

// Round 7
// 99.746 us; speedup vs baseline: 1.0255x; 1.0255x over previous
//
#include <hip/hip_runtime.h>
#include <math.h>
#include <stdint.h>

#define NR    2048   // rows (n)
#define NB    2048   // batch (b)
#define DIMD  64
#define KC    576    // 512 cross + 64 gram
#define BK    64
#define KSTEP 9      // 576 / 64

typedef __bf16 bf16x8 __attribute__((ext_vector_type(8)));
typedef float  f32x4  __attribute__((ext_vector_type(4)));

typedef const __attribute__((address_space(1))) void* gas_p;
typedef __attribute__((address_space(3))) void*       las_p;

__device__ __forceinline__ unsigned short f2bf(float f) {
    unsigned int u = __float_as_uint(f);
    unsigned int r = u + 0x7FFFu + ((u >> 16) & 1u);
    return (unsigned short)(r >> 16);
}

// ---- fused prep: blocks [0,512) build A'/cc/gcg, [512,1024) build B' -------
// block 0 also zeroes d_out (stream order guarantees this precedes the GEMM).
__global__ __launch_bounds__(256) void prep_all(
    const int*   __restrict__ col_indices,
    const float* __restrict__ col_times,
    const float* __restrict__ z_cols,
    const float* __restrict__ gamma_cols,
    const float* __restrict__ z_rows,
    unsigned short* __restrict__ Abuf,
    unsigned short* __restrict__ Bbuf,
    float* __restrict__ cc, float* __restrict__ gcg,
    float* __restrict__ out)
{
    const int tid = threadIdx.x, w = tid >> 6, lane = tid & 63;
    if (blockIdx.x == 0 && tid == 0) *out = 0.f;
    if (blockIdx.x < 512) {
        __shared__ float Tl[4][8];
        const int b  = blockIdx.x * 4 + w;
        const float t  = col_times[b];
        const int   ci = col_indices[b];
        if (lane < 8) {                       // T[o] = t^o / o!
            float v = 1.f;
            for (int i = 1; i <= lane; ++i) v = v * t / (float)i;
            Tl[w][lane] = v;
        }
        __syncthreads();
        const float cd = z_cols[ci * DIMD + lane];
        unsigned short* arow = Abuf + (size_t)b * KC;
#pragma unroll
        for (int o = 0; o < 8; ++o)
            arow[o * 64 + lane] = f2bf(-2.f * Tl[w][o] * cd);
        arow[512 + lane] = f2bf(Tl[w][lane >> 3] * Tl[w][lane & 7]);
        float s = cd * cd;
#pragma unroll
        for (int m = 1; m < 64; m <<= 1) s += __shfl_xor(s, m, 64);
        if (lane == 0) { cc[b] = s; gcg[b] = gamma_cols[ci]; }
    } else {
        const int n = (blockIdx.x - 512) * 4 + w;
        float z8[8];
#pragma unroll
        for (int o = 0; o < 8; ++o)
            z8[o] = z_rows[o * (NR * DIMD) + n * DIMD + lane];
        unsigned short* brow = Bbuf + (size_t)n * KC;
#pragma unroll
        for (int o = 0; o < 8; ++o)
            brow[o * 64 + lane] = f2bf(z8[o]);
        float myG = 0.f;
#pragma unroll
        for (int o1 = 0; o1 < 8; ++o1)
#pragma unroll
            for (int o2 = o1; o2 < 8; ++o2) {
                float p = z8[o1] * z8[o2];
#pragma unroll
                for (int m = 1; m < 64; m <<= 1) p += __shfl_xor(p, m, 64);
                if (lane == o1 * 8 + o2) myG = p;
                if (o1 != o2 && lane == o2 * 8 + o1) myG = p;
            }
        brow[512 + lane] = f2bf(myG);
    }
}

// ---- main: S = A' * B'^T via MFMA, double-buffered 2-phase, fused loss -----
// tile 128(b) x 64(n), BK=64, 4 waves (2x2), wave tile 64x32
// LDS rows 128B: XOR swizzle (pre-swizzled global source + swizzled read,
// linear gload_lds dest). dbuf: STAGE(next) issued before compute(cur),
// single __syncthreads per K-step at loop bottom.
__global__ __launch_bounds__(256, 2) void p2v_gemm(
    const unsigned short* __restrict__ Abuf,
    const unsigned short* __restrict__ Bbuf,
    const float* __restrict__ cc,
    const float* __restrict__ gcg,
    const float* __restrict__ gamma_rows,
    const int*   __restrict__ events,
    float*       __restrict__ out)
{
    __shared__ unsigned short As[2][128 * BK] __attribute__((aligned(16))); // 32KB
    __shared__ unsigned short Bs[2][64 * BK]  __attribute__((aligned(16))); // 16KB
    __shared__ float warr[4];

    const int tid = threadIdx.x, w = tid >> 6, lane = tid & 63;
    const int wm = w >> 1, wn = w & 1;
    const int n0 = blockIdx.x * 64, b0 = blockIdx.y * 128;

    // staging geometry: each gload_lds moves 8 rows x 128B (1KB).
    // lane -> row_local = lane>>3, source 16B chunk = (lane&7) ^ (row&7)
    const int lr8 = lane >> 3;
    const int cx  = (lane & 7) ^ lr8;
    const size_t gA = (size_t)(b0 + w * 32 + lr8) * KC + cx * 8;
    const size_t gB = (size_t)(n0 + w * 16 + lr8) * KC + cx * 8;
    const int dAo = (w * 32) * BK;   // element offsets within a buffer
    const int dBo = (w * 16) * BK;

    f32x4 acc[4][2];
#pragma unroll
    for (int mi = 0; mi < 4; ++mi)
#pragma unroll
        for (int ni = 0; ni < 2; ++ni) acc[mi][ni] = (f32x4)(0.f);

#define STAGE(buf, ks)                                                         \
    {                                                                          \
        const int ko_ = (ks) * BK;                                             \
        _Pragma("unroll")                                                      \
        for (int i = 0; i < 4; ++i)                                            \
            __builtin_amdgcn_global_load_lds(                                  \
                (gas_p)(Abuf + gA + (size_t)(i * 8) * KC + ko_),               \
                (las_p)&As[buf][dAo + i * 512], 16, 0, 0);                     \
        _Pragma("unroll")                                                      \
        for (int i = 0; i < 2; ++i)                                            \
            __builtin_amdgcn_global_load_lds(                                  \
                (gas_p)(Bbuf + gB + (size_t)(i * 8) * KC + ko_),               \
                (las_p)&Bs[buf][dBo + i * 512], 16, 0, 0);                     \
    }

    STAGE(0, 0);
    __syncthreads();

#pragma unroll
    for (int ks = 0; ks < KSTEP; ++ks) {
        const int cur = ks & 1;
        if (ks + 1 < KSTEP) STAGE(cur ^ 1, ks + 1);
#pragma unroll
        for (int kk = 0; kk < 2; ++kk) {
            const int slot = (kk * 4 + (lane >> 4)) ^ (lane & 7);  // ^ (row&7)
            bf16x8 af[4], bfr[2];
#pragma unroll
            for (int mi = 0; mi < 4; ++mi)
                af[mi] = *reinterpret_cast<const bf16x8*>(
                    &As[cur][(wm * 64 + mi * 16 + (lane & 15)) * BK + slot * 8]);
#pragma unroll
            for (int ni = 0; ni < 2; ++ni)
                bfr[ni] = *reinterpret_cast<const bf16x8*>(
                    &Bs[cur][(wn * 32 + ni * 16 + (lane & 15)) * BK + slot * 8]);
#pragma unroll
            for (int mi = 0; mi < 4; ++mi)
#pragma unroll
                for (int ni = 0; ni < 2; ++ni)
                    acc[mi][ni] = __builtin_amdgcn_mfma_f32_16x16x32_bf16(
                        af[mi], bfr[ni], acc[mi][ni], 0, 0, 0);
        }
        __syncthreads();
    }
#undef STAGE

    // epilogue: dist^2 = S + cc[b]; loss = softplus(+/-logit); reduce
    float ls = 0.f;
#pragma unroll
    for (int ni = 0; ni < 2; ++ni) {
        const int n = n0 + wn * 32 + ni * 16 + (lane & 15);
        const float grn = gamma_rows[n];
        const size_t erow = (size_t)n * NB;
#pragma unroll
        for (int mi = 0; mi < 4; ++mi) {
            const int bb = b0 + wm * 64 + mi * 16 + (lane >> 4) * 4;
            const int4   ev  = *reinterpret_cast<const int4*>(&events[erow + bb]);
            const float4 ccv = *reinterpret_cast<const float4*>(&cc[bb]);
            const float4 gcv = *reinterpret_cast<const float4*>(&gcg[bb]);
#define EPJ(cmp, evv)                                                      \
            {                                                              \
                const float d2   = acc[mi][ni].cmp + ccv.cmp;              \
                const float dist = sqrtf(fmaxf(d2, 0.f));                  \
                const float L    = grn + gcv.cmp - dist;                   \
                const float x    = (evv != 0) ? -L : L;                    \
                ls += fmaxf(x, 0.f) + __logf(1.f + __expf(-fabsf(x)));     \
            }
            EPJ(x, ev.x) EPJ(y, ev.y) EPJ(z, ev.z) EPJ(w, ev.w)
#undef EPJ
        }
    }
#pragma unroll
    for (int m = 1; m < 64; m <<= 1) ls += __shfl_xor(ls, m, 64);
    if (lane == 0) warr[w] = ls;
    __syncthreads();
    if (tid == 0) atomicAdd(out, warr[0] + warr[1] + warr[2] + warr[3]);
}

extern "C" void kernel_launch(void* const* d_in, const int* in_sizes, int n_in,
                              void* d_out, int out_size, void* d_ws, size_t ws_size,
                              hipStream_t stream) {
    const int*   events      = (const int*)  d_in[0];
    const int*   col_indices = (const int*)  d_in[1];
    const float* col_times   = (const float*)d_in[2];
    const float* z_rows      = (const float*)d_in[3];
    const float* z_cols      = (const float*)d_in[4];
    const float* gamma_rows  = (const float*)d_in[5];
    const float* gamma_cols  = (const float*)d_in[6];
    float*       out         = (float*)d_out;

    unsigned short* Abuf = (unsigned short*)d_ws;                // 2048*576 bf16
    unsigned short* Bbuf = Abuf + (size_t)NB * KC;               // 2048*576 bf16
    float*          cc   = (float*)(Bbuf + (size_t)NR * KC);     // 2048 f32
    float*          gcg  = cc + NB;                              // 2048 f32

    prep_all<<<1024, 256, 0, stream>>>(col_indices, col_times, z_cols, gamma_cols,
                                       z_rows, Abuf, Bbuf, cc, gcg, out);
    dim3 grid(NR / 64, NB / 128);
    p2v_gemm<<<grid, 256, 0, stream>>>(Abuf, Bbuf, cc, gcg, gamma_rows, events, out);
}